// Round 6
// baseline (181.695 us; speedup 1.0000x reference)
//
#include <hip/hip_runtime.h>
#include <math.h>

#define CIN   128
#define COUT  128
#define KKT   9
#define NSTAT 32768.0f   // B*H*W per-channel count

typedef __attribute__((ext_vector_type(8))) short bf16x8;
typedef __attribute__((ext_vector_type(4))) float f32x4;

__device__ inline unsigned short f2bf(float f) {
    union { float f; unsigned u; } v; v.f = f;
    unsigned r = v.u + 0x7fffu + ((v.u >> 16) & 1u);
    return (unsigned short)(r >> 16);
}
__device__ inline float bflo(unsigned u) { union { unsigned u; float f; } v; v.u = u << 16; return v.f; }
__device__ inline float bfhi(unsigned u) { union { unsigned u; float f; } v; v.u = u & 0xffff0000u; return v.f; }

// barrier that does NOT drain vmcnt -> pipelined global loads stay in flight
#define FAST_BARRIER() asm volatile("s_waitcnt lgkmcnt(0)\n\ts_barrier" ::: "memory")

// ---------------- ws layout (bytes) ----------------
// xt  : 16777216   bf16 channel-last x[b][y][x][c], stored as dword c-pairs
// wb  : 294912     [oc][kt*128+c] bf16   (main conv A)
// wob : 73728      [32 ocpad][kt*128+c] bf16 (offset conv A, rows 18..31 zero)
// sums: 512 B      sums|sumsq

// Fused prep: blocks 0..511 transpose x -> xt; blocks 512+ repack weights + zero stats
__global__ __launch_bounds__(512) void prep_all_k(const float* __restrict__ x,
                                                  const float* __restrict__ w_def,
                                                  const float* __restrict__ w_off,
                                                  unsigned* __restrict__ xt,
                                                  unsigned short* __restrict__ wb,
                                                  unsigned short* __restrict__ wob,
                                                  float* __restrict__ sums) {
    const int blk = blockIdx.x;
    if (blk < 512) {
        __shared__ float lt[128][65];
        const int by = blk;              // b*64 + y
        const int b = by >> 6, y = by & 63;
        const int t = threadIdx.x, l = t & 63, g8 = t >> 6;
        const float* xb = x + (b * 128) * 4096 + y * 64;
#pragma unroll
        for (int pass = 0; pass < 16; pass++) {
            int c = pass * 8 + g8;
            lt[c][l] = xb[c * 4096 + l];
        }
        __syncthreads();
        unsigned* xo = xt + (by * 64) * 64;
#pragma unroll
        for (int pass = 0; pass < 8; pass++) {
            int w = pass * 8 + g8;
            float f0 = lt[2 * l][w], f1 = lt[2 * l + 1][w];
            xo[w * 64 + l] = (unsigned)f2bf(f0) | ((unsigned)f2bf(f1) << 16);
        }
    } else {
        int i = (blk - 512) * 512 + threadIdx.x;
        if (i < 147456) {
            int oc = i / 1152, r = i - oc * 1152, kt = r >> 7, c = r & 127;
            wb[i] = f2bf(w_def[(oc * 128 + c) * 9 + kt]);
        } else if (i < 147456 + 36864) {
            int j = i - 147456;
            int ocp = j / 1152, r = j - ocp * 1152, kt = r >> 7, c = r & 127;
            wob[j] = (ocp < 18) ? f2bf(w_off[(ocp * 128 + c) * 9 + kt]) : (unsigned short)0;
        } else if (i < 147456 + 36864 + 256) {
            sums[i - 147456 - 36864] = 0.f;
        }
    }
}

#define RB 51200
// One block per (b,h), XCD-swizzled. 512 threads = 8 waves.
__global__ __launch_bounds__(512, 4) void deform_main_k(const unsigned* __restrict__ xt,
                                                        const unsigned short* __restrict__ wb,
                                                        const unsigned short* __restrict__ wob,
                                                        const float* __restrict__ b_def,
                                                        float* __restrict__ out,
                                                        float* __restrict__ sums,
                                                        float* __restrict__ sumsq) {
    __shared__ __align__(16) unsigned char smem[RB + 4608 + 1024];
    unsigned short* xrow = (unsigned short*)smem;              // [3][66][128] bf16, 50688 B (phase 0 only)
    int*            tab  = (int*)smem;                         // [9*64][8] dwords, 18432 B (aliases xrow)
    unsigned short* samp0 = (unsigned short*)(smem + 18432);   // [64][128] bf16
    unsigned short* samp1 = (unsigned short*)(smem + 34816);
    float* offl = (float*)(smem + RB);                         // [18][64]
    float* stat = (float*)(smem + RB + 4608);                  // [256]

    const int t    = threadIdx.x;
    const int bh   = blockIdx.x;
    const int b    = bh >> 6;
    const int j_   = bh & 63;
    const int h    = ((j_ & 7) << 3) | (j_ >> 3);   // XCD-locality swizzle
    const int lane = t & 63;
    const int wv   = __builtin_amdgcn_readfirstlane(t >> 6);  // 0..7
    const int quad = lane >> 4, lo = lane & 15;
    const int l    = lane;        // c-pair index for gathers
    const int g    = lane >> 2;   // c-group of 8

    if (t < 256) stat[t] = 0.f;

    const unsigned* xtb = xt + b * 262144;   // dwords per batch image

    // ---- stage xrow: rows h-1..h+1, x = -1..64, zero-padded, swizzled ----
    for (int p = wv; p < 198; p += 8) {
        int r = p / 66, xi = p - r * 66;
        int y = h + r - 1, x = xi - 1;
        unsigned u = 0;
        if ((unsigned)y < 64u && (unsigned)x < 64u) u = xtb[(y * 64 + x) * 64 + l];
        ((unsigned*)xrow)[(r * 66 + xi) * 64 + ((g ^ (xi & 15)) << 2) + (l & 3)] = u;
    }
    __syncthreads();

    // ---- offset conv via MFMA: wave -> (mt = wv>>2, nt = wv&3), D[oc][w] ----
    {
        const int mt = wv >> 2, nt = wv & 3;
        f32x4 ao = {0.f, 0.f, 0.f, 0.f};
        const unsigned short* wrow = wob + (mt * 16 + lo) * 1152 + quad * 8;
        for (int kt = 0; kt < 9; kt++) {
            int ky = kt / 3, kx = kt - ky * 3;
            int xi = nt * 16 + lo + kx;
#pragma unroll
            for (int ch = 0; ch < 4; ch++) {
                int gg = ch * 4 + quad;
                bf16x8 af = *(const bf16x8*)(wrow + kt * 128 + ch * 32);
                bf16x8 bf = *(const bf16x8*)(xrow + (ky * 66 + xi) * 128 + ((gg ^ (xi & 15)) << 3));
                ao = __builtin_amdgcn_mfma_f32_16x16x32_bf16(af, bf, ao, 0, 0, 0);
            }
        }
        __syncthreads();   // all waves done reading xrow
#pragma unroll
        for (int r = 0; r < 4; r++) {
            int oc = mt * 16 + quad * 4 + r;
            if (oc < 18) offl[oc * 64 + nt * 16 + lo] = ao[r];
        }
    }
    __syncthreads();   // offl ready; xrow region free for tab

    // ---- tap tables: 4 pixel dword-offsets + 4 weights per (tap,w) ----
    for (int i = t; i < KKT * 64; i += 512) {
        int k = i >> 6, w2 = i & 63;
        float dy = offl[(2 * k) * 64 + w2];
        float dx = offl[(2 * k + 1) * 64 + w2];
        int ky = k / 3, kx = k - ky * 3;
        float ys = (float)(h - 1 + ky) + dy;
        float xs = (float)(w2 - 1 + kx) + dx;
        float y0f = floorf(ys), x0f = floorf(xs);
        float wyf = ys - y0f, wxf = xs - x0f;
        int iy0 = (int)y0f, ix0 = (int)x0f;
        int cy0 = min(max(iy0, 0), 63), cy1 = min(max(iy0 + 1, 0), 63);
        int px  = min(max(ix0, 0), 63), px2 = min(max(ix0 + 1, 0), 63);
        float wy0 = (iy0 >= 0 && iy0 < 64) ? (1.f - wyf) : 0.f;
        float wy1 = (iy0 + 1 >= 0 && iy0 + 1 < 64) ? wyf : 0.f;
        float wa  = (ix0 >= 0 && ix0 < 64) ? (1.f - wxf) : 0.f;
        float wbv = (ix0 + 1 >= 0 && ix0 + 1 < 64) ? wxf : 0.f;
        int base = i * 8;
        tab[base + 0] = (cy0 * 64 + px ) * 64;
        tab[base + 1] = (cy0 * 64 + px2) * 64;
        tab[base + 2] = (cy1 * 64 + px ) * 64;
        tab[base + 3] = (cy1 * 64 + px2) * 64;
        ((float*)tab)[base + 4] = wy0;
        ((float*)tab)[base + 5] = wy1;
        ((float*)tab)[base + 6] = wa;
        ((float*)tab)[base + 7] = wbv;
    }
    __syncthreads();

    // ---- main tap loop: software-pipelined coalesced gather + dbuf samp + MFMA ----
    const int m0 = wv >> 1, n0 = wv & 1;
    f32x4 acc[2][2];
#pragma unroll
    for (int i = 0; i < 2; i++)
#pragma unroll
        for (int j = 0; j < 2; j++)
#pragma unroll
            for (int r = 0; r < 4; r++) acc[i][j][r] = 0.f;

    const unsigned short* wrow0 = wb + (2 * m0 * 16 + lo) * 1152 + quad * 8;
    const unsigned short* wrow1 = wrow0 + 16 * 1152;

    unsigned gr[32];      // gather data for current tap: [i=w-local][corner]
    bf16x8 afA[4], afB[4];

    // prologue: prefetch tap 0 gathers + A-fragments
#pragma unroll
    for (int i = 0; i < 8; i++) {
        int w = wv * 8 + i;
        int4 ta = *(const int4*)&tab[(0 * 64 + w) * 8];
        gr[i * 4 + 0] = xtb[ta.x + l];
        gr[i * 4 + 1] = xtb[ta.y + l];
        gr[i * 4 + 2] = xtb[ta.z + l];
        gr[i * 4 + 3] = xtb[ta.w + l];
    }
#pragma unroll
    for (int ch = 0; ch < 4; ch++) {
        afA[ch] = *(const bf16x8*)(wrow0 + 0 * 128 + ch * 32);
        afB[ch] = *(const bf16x8*)(wrow1 + 0 * 128 + ch * 32);
    }

    for (int kt = 0; kt < KKT; kt++) {
        // interp tap kt from registers (weights re-read: wave-uniform LDS broadcast)
        unsigned* sb = (unsigned*)((kt & 1) ? samp1 : samp0);
#pragma unroll
        for (int i = 0; i < 8; i++) {
            int w = wv * 8 + i;
            float4 tw = *(const float4*)&tab[(kt * 64 + w) * 8 + 4];
            unsigned u00 = gr[i * 4 + 0], u01 = gr[i * 4 + 1];
            unsigned u10 = gr[i * 4 + 2], u11 = gr[i * 4 + 3];
            float e = tw.x * (tw.z * bflo(u00) + tw.w * bflo(u01)) +
                      tw.y * (tw.z * bflo(u10) + tw.w * bflo(u11));
            float o = tw.x * (tw.z * bfhi(u00) + tw.w * bfhi(u01)) +
                      tw.y * (tw.z * bfhi(u10) + tw.w * bfhi(u11));
            sb[w * 64 + ((g ^ (w & 15)) << 2) + (l & 3)] =
                (unsigned)f2bf(e) | ((unsigned)f2bf(o) << 16);
        }
        // prefetch tap kt+1 gathers (reuse gr; in flight across barrier + MFMA)
        if (kt < KKT - 1) {
#pragma unroll
            for (int i = 0; i < 8; i++) {
                int w = wv * 8 + i;
                int4 ta = *(const int4*)&tab[((kt + 1) * 64 + w) * 8];
                gr[i * 4 + 0] = xtb[ta.x + l];
                gr[i * 4 + 1] = xtb[ta.y + l];
                gr[i * 4 + 2] = xtb[ta.z + l];
                gr[i * 4 + 3] = xtb[ta.w + l];
            }
        }
        FAST_BARRIER();
        // MFMA phase: zero global loads -> no vmcnt drain here
        const unsigned short* sbs = (kt & 1) ? samp1 : samp0;
#pragma unroll
        for (int ch = 0; ch < 4; ch++) {
            int gg = ch * 4 + quad;
            int r0 = (2 * n0 + 0) * 16 + lo, r1 = (2 * n0 + 1) * 16 + lo;
            bf16x8 bf0 = *(const bf16x8*)(sbs + r0 * 128 + ((gg ^ lo) << 3));
            bf16x8 bf1 = *(const bf16x8*)(sbs + r1 * 128 + ((gg ^ lo) << 3));
            acc[0][0] = __builtin_amdgcn_mfma_f32_16x16x32_bf16(afA[ch], bf0, acc[0][0], 0, 0, 0);
            acc[0][1] = __builtin_amdgcn_mfma_f32_16x16x32_bf16(afA[ch], bf1, acc[0][1], 0, 0, 0);
            acc[1][0] = __builtin_amdgcn_mfma_f32_16x16x32_bf16(afB[ch], bf0, acc[1][0], 0, 0, 0);
            acc[1][1] = __builtin_amdgcn_mfma_f32_16x16x32_bf16(afB[ch], bf1, acc[1][1], 0, 0, 0);
        }
        // prefetch tap kt+1 A-fragments (covered by next gather/interp phase)
        if (kt < KKT - 1) {
#pragma unroll
            for (int ch = 0; ch < 4; ch++) {
                afA[ch] = *(const bf16x8*)(wrow0 + (kt + 1) * 128 + ch * 32);
                afB[ch] = *(const bf16x8*)(wrow1 + (kt + 1) * 128 + ch * 32);
            }
        }
    }

    // ---- epilogue: bias + store + fused BN stats ----
    float* ob = out + b * COUT * 4096 + h * 64;
#pragma unroll
    for (int mt2 = 0; mt2 < 2; mt2++) {
        int ocb = (2 * m0 + mt2) * 16 + quad * 4;
#pragma unroll
        for (int r = 0; r < 4; r++) {
            int oc = ocb + r;
            float bia = b_def[oc];
            float ssum = 0.f, qsum = 0.f;
#pragma unroll
            for (int nt2 = 0; nt2 < 2; nt2++) {
                int w_ = (2 * n0 + nt2) * 16 + lo;
                float v = acc[mt2][nt2][r] + bia;
                ob[oc * 4096 + w_] = v;
                ssum += v; qsum += v * v;
            }
#pragma unroll
            for (int d = 1; d < 16; d <<= 1) {
                ssum += __shfl_xor(ssum, d, 64);
                qsum += __shfl_xor(qsum, d, 64);
            }
            if (lo == 0) { atomicAdd(&stat[oc], ssum); atomicAdd(&stat[128 + oc], qsum); }
        }
    }
    __syncthreads();
    if (t < 256) {
        float* gp = (t < 128) ? (sums + t) : (sumsq + (t - 128));
        atomicAdd(gp, stat[t]);
    }
}

__global__ __launch_bounds__(256) void bn_silu_k(float* __restrict__ out,
                                                 const float* __restrict__ sums,
                                                 const float* __restrict__ sumsq,
                                                 const float* __restrict__ gamma,
                                                 const float* __restrict__ beta) {
    __shared__ float sc_s[128], sh_s[128];
    int t = threadIdx.x;
    if (t < 128) {
        const float invN = 1.f / NSTAT;
        float m = sums[t] * invN;
        float v = fmaf(-m, m, sumsq[t] * invN);
        float sc = gamma[t] * rsqrtf(v + 1e-5f);
        sc_s[t] = sc;
        sh_s[t] = beta[t] - m * sc;
    }
    __syncthreads();
    int i = blockIdx.x * 256 + t;
    float4 v = ((float4*)out)[i];
    int oc = (i >> 10) & 127;
    float sc = sc_s[oc], sh = sh_s[oc];
    float z0 = v.x * sc + sh;
    float z1 = v.y * sc + sh;
    float z2 = v.z * sc + sh;
    float z3 = v.w * sc + sh;
    v.x = z0 / (1.f + __expf(-z0));
    v.y = z1 / (1.f + __expf(-z1));
    v.z = z2 / (1.f + __expf(-z2));
    v.w = z3 / (1.f + __expf(-z3));
    ((float4*)out)[i] = v;
}

extern "C" void kernel_launch(void* const* d_in, const int* in_sizes, int n_in,
                              void* d_out, int out_size, void* d_ws, size_t ws_size,
                              hipStream_t stream) {
    const float* x     = (const float*)d_in[0];
    const float* w_off = (const float*)d_in[1];
    const float* w_def = (const float*)d_in[2];
    const float* b_def = (const float*)d_in[3];
    const float* gamma = (const float*)d_in[4];
    const float* beta  = (const float*)d_in[5];
    float* out = (float*)d_out;

    unsigned*       xt   = (unsigned*)d_ws;                               // 16777216 B
    unsigned short* wb   = (unsigned short*)((char*)d_ws + 16777216);     // 294912 B
    unsigned short* wob  = (unsigned short*)((char*)d_ws + 17072128);     // 73728 B
    float*          sums = (float*)((char*)d_ws + 17145856);              // 128
    float*          sumsq = sums + 128;

    prep_all_k<<<873, 512, 0, stream>>>(x, w_def, w_off, xt, wb, wob, sums);
    deform_main_k<<<512, 512, 0, stream>>>(xt, wb, wob, b_def, out, sums, sumsq);
    bn_silu_k<<<4096, 256, 0, stream>>>(out, sums, sumsq, gamma, beta);
}